// Round 7
// baseline (491.461 us; speedup 1.0000x reference)
//
#include <hip/hip_runtime.h>
#include <hip/hip_bf16.h>

typedef unsigned short u16;
typedef unsigned int u32;
typedef __attribute__((ext_vector_type(8))) short short8;
typedef __attribute__((ext_vector_type(4))) float f32x4;

// Round-to-nearest-even f32 -> bf16 bit pattern.
__device__ __forceinline__ u16 f2bf(float f) {
    union { float f; u32 u; } c; c.f = f;
    u32 x = c.u;
    return (u16)((x + 0x7fffu + ((x >> 16) & 1u)) >> 16);
}

// Async global->LDS, 16 bytes per lane. LDS dest must be wave-uniform base
// (HW writes base + lane*16); global src is per-lane.
__device__ __forceinline__ void gload16(const void* g, void* l) {
    __builtin_amdgcn_global_load_lds((const __attribute__((address_space(1))) void*)g,
                                     (__attribute__((address_space(3))) void*)l,
                                     16, 0, 0);
}

// All f32->bf16 conversions in one launch: blocks 0..4095 convert x,
// blocks 4096..8191 convert the four 1024x1024 weights (Wq,Wk,Wv->wqkv; Wo->wob).
__global__ void cvt_all_kernel(const float* __restrict__ x,
                               const float* __restrict__ wq, const float* __restrict__ wk,
                               const float* __restrict__ wv, const float* __restrict__ wo,
                               u16* __restrict__ xb, u16* __restrict__ wqkv,
                               u16* __restrict__ wob) {
    int bid = blockIdx.x;
    const float* src;
    u16* dst;
    int i;
    if (bid < 4096) {
        src = x; dst = xb;
        i = bid * 256 + threadIdx.x;
    } else {
        int w = (bid - 4096) >> 10;
        src = (w == 0) ? wq : (w == 1) ? wk : (w == 2) ? wv : wo;
        dst = (w < 3) ? (wqkv + (size_t)w * 1048576) : wob;
        i = ((bid - 4096) & 1023) * 256 + threadIdx.x;
    }
    float4 v = reinterpret_cast<const float4*>(src)[i];
    ushort4 o;
    o.x = f2bf(v.x); o.y = f2bf(v.y); o.z = f2bf(v.z); o.w = f2bf(v.w);
    reinterpret_cast<ushort4*>(dst)[i] = o;
}

// C(4096 x Ncols) = A(4096x1024) * B^T, B row-major (Ncols x 1024).
// m97 structure: global_load_lds dwordx4 staging, linear LDS + XOR-swizzled reads.
// MODE 0: f32 row-major to outf (Ncols=1024)
// MODE 1: fused QKV (Ncols=3072): gj>>10 selects Q / K / V-transposed layout.
//         Q is pre-scaled by 0.125*log2(e) so attention scores land in log2 units.
template<int MODE>
__global__ __launch_bounds__(256, 3) void gemm_nt(const u16* __restrict__ A,
                                                  const u16* __restrict__ Bw,
                                                  u16* __restrict__ qkv,
                                                  float* __restrict__ outf) {
    constexpr int K = 1024;
    __shared__ __align__(16) u16 Al[128 * 64];
    __shared__ __align__(16) u16 Bl[128 * 64];
    const int tid = threadIdx.x;
    const int row0 = blockIdx.y * 128, col0 = blockIdx.x * 128;
    const int wid = tid >> 6, lane = tid & 63;
    const int wr = wid >> 1, wc = wid & 1;       // 2x2 waves, each 64x64 output
    const int lr = lane & 15, lg = lane >> 4;
    f32x4 acc[4][4] = {};

    const int srow = tid >> 3;                   // staging row within 32-row group
    const int sslotbase = tid & 7;

    for (int kt = 0; kt < K; kt += 64) {
        __syncthreads();                         // prev compute done before overwrite
        #pragma unroll
        for (int i = 0; i < 4; ++i) {
            int row = srow + i * 32;
            int srcslot = sslotbase ^ (row & 7); // pre-swizzled source -> linear LDS dest
            int ldsoff = i * 2048 + wid * 512;   // u16 units; wave-uniform
            gload16(&A[(size_t)(row0 + row) * K + kt + srcslot * 8], &Al[ldsoff]);
            gload16(&Bw[(size_t)(col0 + row) * K + kt + srcslot * 8], &Bl[ldsoff]);
        }
        __syncthreads();                         // vmcnt(0) drained by compiler

        #pragma unroll
        for (int ks = 0; ks < 2; ++ks) {
            short8 af[4], bfr[4];
            #pragma unroll
            for (int m = 0; m < 4; ++m) {
                int row = wr * 64 + m * 16 + lr;
                af[m] = *reinterpret_cast<const short8*>(
                    &Al[row * 64 + (((ks * 4 + lg) ^ (lr & 7)) << 3)]);
            }
            #pragma unroll
            for (int n = 0; n < 4; ++n) {
                int row = wc * 64 + n * 16 + lr;
                bfr[n] = *reinterpret_cast<const short8*>(
                    &Bl[row * 64 + (((ks * 4 + lg) ^ (lr & 7)) << 3)]);
            }
            #pragma unroll
            for (int m = 0; m < 4; ++m)
                #pragma unroll
                for (int n = 0; n < 4; ++n)
                    acc[m][n] = __builtin_amdgcn_mfma_f32_16x16x32_bf16(af[m], bfr[n], acc[m][n], 0, 0, 0);
        }
    }

    #pragma unroll
    for (int m = 0; m < 4; ++m) {
        #pragma unroll
        for (int n = 0; n < 4; ++n) {
            #pragma unroll
            for (int r = 0; r < 4; ++r) {
                int gi = row0 + wr * 64 + m * 16 + lg * 4 + r;   // row = (lane>>4)*4+reg
                int gj = col0 + wc * 64 + n * 16 + lr;           // col = lane&15
                float v = acc[m][n][r];
                if (MODE == 0) {
                    outf[(size_t)gi * 1024 + gj] = v;
                } else {
                    int mat = gj >> 10, c = gj & 1023;
                    int h = c >> 6, hd = c & 63;
                    int b = gi >> 11, s = gi & 2047;
                    if (mat == 0) v *= 0.18033688f;   // Q *= 0.125*log2(e)
                    size_t idx;
                    if (mat < 2) idx = (((size_t)(b * 16 + h) * 2048) + s) * 64 + hd;   // Q,K: (B,H,S,HD)
                    else         idx = (((size_t)(b * 16 + h) * 64) + hd) * 2048 + s;   // V: (B,H,HD,S)
                    qkv[(size_t)mat * 4194304 + idx] = f2bf(v);
                }
            }
        }
    }
}

// Flash attention + ALiBi + causal.
// 4 waves/block = (row-half rhalf) x (tile-parity thalf). Each wave: 16-row slices
// of the balanced pair {p, mirror(p)}, tiles t = thalf, thalf+2, ... descending
// (diagonal-first). K/V read DIRECT from global (L2-resident per-XCD working set;
// no LDS staging, no in-loop barriers; 1-iter register prefetch). Fixed local
// ALiBi bias in MFMA C; global bias offset absorbed in drifting m (+=128*slope2
// per iter). l via ones-MFMA. Defer-max. Two KV-half partials merged in-block
// via LDS at the end (single __syncthreads in the kernel).
// Grid: 1024 blocks x 256, XCD-swizzled (each XCD sees 4 bh).
__global__ __launch_bounds__(256, 4) void attn_kernel(const u16* __restrict__ Q,
                                                      const u16* __restrict__ Kt,
                                                      const u16* __restrict__ VT,
                                                      u16* __restrict__ attn) {
    constexpr int S = 2048;
    __shared__ __align__(16) u16 Pl[8][16 * 64];        // per (wave, strip) P buffer
    __shared__ __align__(16) float Ol[2][2][64 * 16];   // merge: [rhalf][st][d*16+q]
    __shared__ float Ml[2][2][16];
    __shared__ float Ll[2][2][16];
    const int gid = blockIdx.x;
    const int base = gid >> 3, xcd = gid & 7;
    const int bh = xcd * 4 + (base >> 5);               // XCD x gets bh in [4x, 4x+4)
    const int p  = base & 31;                           // pair index 0..31
    const int b = bh >> 4, h = bh & 15;
    const int tid = threadIdx.x, wid = tid >> 6, lane = tid & 63;
    const int rhalf = wid & 1, thalf = wid >> 1;
    const int lr = lane & 15, lg = lane >> 4;
    const float slope2 = exp2f(-0.5f * (float)(h + 1)) * 1.44269504f;  // slope*log2(e)
    const int nt  = (2111 - 32 * p) >> 6;               // hi strip needs tiles 0..nt-1
    const int nlo = ((32 * p + 31) >> 6) + 1;           // lo strip active for t < nlo
    const int rowlo = 32 * p + rhalf * 16;
    const int rowhi = S - 32 * p - 32 + rhalf * 16;
    const size_t qkbase = (size_t)bh * S * 64;
    const size_t vbase  = (size_t)bh * 64 * S;

    // Q fragments (pre-scaled by 0.125*log2e in the GEMM epilogue)
    short8 qf[2][2];
    #pragma unroll
    for (int st = 0; st < 2; ++st) {
        int rb = st ? rowhi : rowlo;
        #pragma unroll
        for (int ks = 0; ks < 2; ++ks)
            qf[st][ks] = *reinterpret_cast<const short8*>(
                &Q[qkbase + (size_t)(rb + lr) * 64 + ks * 32 + lg * 8]);
    }

    // Fixed LOCAL bias (tile- and strip-independent); global part drifts in m.
    f32x4 bias[4];
    #pragma unroll
    for (int n = 0; n < 4; ++n)
        #pragma unroll
        for (int r = 0; r < 4; ++r)
            bias[n][r] = slope2 * (float)((n * 16 + lr) - (lg * 4 + r));

    const float mstep = slope2 * 128.f;   // shift growth per 2-tile step
    float m_run[2][4];
    f32x4 o_acc[2][4] = {};
    f32x4 l_acc[2] = {};
    #pragma unroll
    for (int st = 0; st < 2; ++st)
        #pragma unroll
        for (int r = 0; r < 4; ++r) m_run[st][r] = -1e30f;

    short8 bones = (short8)(short)0x3F80;   // bf16 1.0 splat (l = P @ ones)

    // K/V fragments live in registers; reloaded (prefetched) each iter.
    short8 kc[4][2], vc[4][2];
    #define LOADK(kv0_)                                                               \
        do {                                                                          \
            _Pragma("unroll")                                                         \
            for (int n_ = 0; n_ < 4; ++n_) {                                          \
                _Pragma("unroll")                                                     \
                for (int ks_ = 0; ks_ < 2; ++ks_)                                     \
                    kc[n_][ks_] = *reinterpret_cast<const short8*>(                   \
                        &Kt[qkbase + (size_t)((kv0_) + n_ * 16 + lr) * 64 +           \
                            ks_ * 32 + lg * 8]);                                      \
            }                                                                         \
        } while (0)
    #define LOADV(kv0_)                                                               \
        do {                                                                          \
            _Pragma("unroll")                                                         \
            for (int n_ = 0; n_ < 4; ++n_) {                                          \
                _Pragma("unroll")                                                     \
                for (int ks_ = 0; ks_ < 2; ++ks_)                                     \
                    vc[n_][ks_] = *reinterpret_cast<const short8*>(                   \
                        &VT[vbase + (size_t)(n_ * 16 + lr) * S + (kv0_) +             \
                            ks_ * 32 + lg * 8]);                                      \
            }                                                                         \
        } while (0)

    // softmax for one strip: defer-max common path has NO cross-lane ops.
    auto softmax = [&](f32x4* sacc, int st, bool domask, int rowbase, int kv0) {
        float* mr = m_run[st];
        if (domask) {
            #pragma unroll
            for (int n = 0; n < 4; ++n)
                #pragma unroll
                for (int r = 0; r < 4; ++r) {
                    int gc = kv0 + n * 16 + lr, gr = rowbase + lg * 4 + r;
                    if (gc > gr) sacc[n][r] = -1e30f;
                }
        }
        float mxl[4];
        #pragma unroll
        for (int r = 0; r < 4; ++r)
            mxl[r] = fmaxf(fmaxf(sacc[0][r], sacc[1][r]), fmaxf(sacc[2][r], sacc[3][r]));
        int ok = (mxl[0] <= mr[0] + 8.f) && (mxl[1] <= mr[1] + 8.f) &&
                 (mxl[2] <= mr[2] + 8.f) && (mxl[3] <= mr[3] + 8.f);
        if (!__all(ok)) {
            #pragma unroll
            for (int r = 0; r < 4; ++r) {
                float mx = mxl[r];
                mx = fmaxf(mx, __shfl_xor(mx, 1));
                mx = fmaxf(mx, __shfl_xor(mx, 2));
                mx = fmaxf(mx, __shfl_xor(mx, 4));
                mx = fmaxf(mx, __shfl_xor(mx, 8));
                float mnew = fmaxf(mr[r], mx);
                float resc = exp2f(mr[r] - mnew);
                mr[r] = mnew;
                l_acc[st][r] *= resc;
                #pragma unroll
                for (int nd = 0; nd < 4; ++nd) o_acc[st][nd][r] *= resc;
            }
        }
        u16* pb = &Pl[wid * 2 + st][0];
        #pragma unroll
        for (int r = 0; r < 4; ++r) {
            int pr = lg * 4 + r;
            #pragma unroll
            for (int n = 0; n < 4; ++n) {
                float pe = exp2f(sacc[n][r] - mr[r]);
                // round-half-up cvt: bias cancels exactly in O/l (same P feeds both)
                u32 bits = __float_as_uint(pe);
                int pc = n * 16 + lr;
                pb[pr * 64 + (((pc >> 3) ^ (pr & 7)) << 3) + (pc & 7)] =
                    (u16)((bits + 0x8000u) >> 16);
            }
        }
    };

    const int t0 = (((nt - 1) & 1) == thalf) ? (nt - 1) : (nt - 2);
    LOADK(t0 * 64);
    LOADV(t0 * 64);

    for (int t = t0; t >= 0; t -= 2) {           // diagonal-first, stride 2 (my parity)
        const int kv0 = t * 64;
        #pragma unroll
        for (int st = 0; st < 2; ++st)
            #pragma unroll
            for (int r = 0; r < 4; ++r) m_run[st][r] += mstep;   // track shift growth
        const bool lo_on = (t < nlo);

        // ---- S = Q K^T (C-init = fixed local bias) ----
        f32x4 shi[4], slo[4];
        __builtin_amdgcn_s_setprio(1);
        #pragma unroll
        for (int ks = 0; ks < 2; ++ks) {
            #pragma unroll
            for (int n = 0; n < 4; ++n)
                shi[n] = __builtin_amdgcn_mfma_f32_16x16x32_bf16(qf[1][ks], kc[n][ks],
                                                                 ks ? shi[n] : bias[n], 0, 0, 0);
            if (lo_on)
                #pragma unroll
                for (int n = 0; n < 4; ++n)
                    slo[n] = __builtin_amdgcn_mfma_f32_16x16x32_bf16(qf[0][ks], kc[n][ks],
                                                                     ks ? slo[n] : bias[n], 0, 0, 0);
        }
        __builtin_amdgcn_s_setprio(0);
        if (t >= 2) LOADK(kv0 - 128);            // prefetch K(t-2); lands under softmax+PV

        softmax(shi, 1, t == nt - 1, rowhi, kv0);
        if (lo_on) softmax(slo, 0, t == nlo - 1, rowlo, kv0);

        // ---- O += P V; l += P @ 1 ----
        __builtin_amdgcn_s_setprio(1);
        #pragma unroll
        for (int ks = 0; ks < 2; ++ks) {
            const int sz = ((ks * 4 + lg) ^ (lr & 7)) << 3;
            short8 ah = *reinterpret_cast<const short8*>(&Pl[wid * 2 + 1][lr * 64 + sz]);
            #pragma unroll
            for (int nd = 0; nd < 4; ++nd)
                o_acc[1][nd] = __builtin_amdgcn_mfma_f32_16x16x32_bf16(ah, vc[nd][ks], o_acc[1][nd], 0, 0, 0);
            l_acc[1] = __builtin_amdgcn_mfma_f32_16x16x32_bf16(ah, bones, l_acc[1], 0, 0, 0);
            if (lo_on) {
                short8 al = *reinterpret_cast<const short8*>(&Pl[wid * 2 + 0][lr * 64 + sz]);
                #pragma unroll
                for (int nd = 0; nd < 4; ++nd)
                    o_acc[0][nd] = __builtin_amdgcn_mfma_f32_16x16x32_bf16(al, vc[nd][ks], o_acc[0][nd], 0, 0, 0);
                l_acc[0] = __builtin_amdgcn_mfma_f32_16x16x32_bf16(al, bones, l_acc[0], 0, 0, 0);
            }
        }
        __builtin_amdgcn_s_setprio(0);
        if (t >= 2) LOADV(kv0 - 128);            // prefetch V(t-2); lands under next QK
    }
    #undef LOADK
    #undef LOADV

    // ---- merge the two KV-half partials (waves thalf=0 <- thalf=1) ----
    // m is in the shifted domain; convert to true domain: sigma_end = slope2*(rowbase - 64*thalf).
    if (thalf == 1) {
        #pragma unroll
        for (int st = 0; st < 2; ++st) {
            int rb = st ? rowhi : rowlo;
            if (lr == 0) {
                #pragma unroll
                for (int r = 0; r < 4; ++r) {
                    Ml[rhalf][st][lg * 4 + r] = m_run[st][r] - slope2 * (float)(rb - 64);
                    Ll[rhalf][st][lg * 4 + r] = l_acc[st][r];
                }
            }
            #pragma unroll
            for (int nd = 0; nd < 4; ++nd)
                *reinterpret_cast<f32x4*>(&Ol[rhalf][st][(nd * 16 + lr) * 16 + lg * 4]) = o_acc[st][nd];
        }
    }
    __syncthreads();
    if (thalf == 0) {
        #pragma unroll
        for (int st = 0; st < 2; ++st) {
            int rb = st ? rowhi : rowlo;
            f32x4 o1[4];
            #pragma unroll
            for (int nd = 0; nd < 4; ++nd)
                o1[nd] = *reinterpret_cast<const f32x4*>(&Ol[rhalf][st][(nd * 16 + lr) * 16 + lg * 4]);
            #pragma unroll
            for (int r = 0; r < 4; ++r) {
                float mt = m_run[st][r] - slope2 * (float)rb;   // t_end = 0
                float m1 = Ml[rhalf][st][lg * 4 + r];
                float M  = fmaxf(mt, m1);
                float e0 = exp2f(mt - M), e1 = exp2f(m1 - M);
                float L  = l_acc[st][r] * e0 + Ll[rhalf][st][lg * 4 + r] * e1;
                float inv = 1.f / L;
                int gs = rb + lg * 4 + r;
                size_t obase = ((size_t)b * S + gs) * 1024 + h * 64;
                #pragma unroll
                for (int nd = 0; nd < 4; ++nd)
                    attn[obase + nd * 16 + lr] = f2bf((o_acc[st][nd][r] * e0 + o1[nd][r] * e1) * inv);
            }
        }
    }
}

extern "C" void kernel_launch(void* const* d_in, const int* in_sizes, int n_in,
                              void* d_out, int out_size, void* d_ws, size_t ws_size,
                              hipStream_t stream) {
    const float* x  = (const float*)d_in[0];
    // d_in[1] is the causal mask (fixed tril) — implemented analytically.
    const float* Wq = (const float*)d_in[2];
    const float* Wk = (const float*)d_in[3];
    const float* Wv = (const float*)d_in[4];
    const float* Wo = (const float*)d_in[5];

    u16* xb   = (u16*)d_ws;            // 4,194,304  (also reused as Ab)
    u16* wqkv = xb + 4194304;          // 3,145,728  (Wq;Wk;Wv rows)
    u16* wob  = wqkv + 3145728;        // 1,048,576
    u16* Qb   = wob + 1048576;         // 4,194,304  (B,H,S,HD)
    u16* Kb   = Qb + 4194304;          // 4,194,304  (B,H,S,HD)
    u16* VTb  = Kb + 4194304;          // 4,194,304  (B,H,HD,S)
    u16* Ab   = xb;                    // attn output reuses xb (x no longer needed)

    cvt_all_kernel<<<8192, 256, 0, stream>>>(x, Wq, Wk, Wv, Wo, xb, wqkv, wob);

    gemm_nt<1><<<dim3(24, 32), 256, 0, stream>>>(xb, wqkv, Qb, nullptr);   // fused QKV

    attn_kernel<<<1024, 256, 0, stream>>>(Qb, Kb, VTb, Ab);

    gemm_nt<0><<<dim3(8, 32), 256, 0, stream>>>(Ab, wob, nullptr, (float*)d_out);
}

// Round 8
// 121.672 us; speedup vs baseline: 4.0392x; 4.0392x over previous
//
#include <hip/hip_runtime.h>
#include <hip/hip_bf16.h>

typedef unsigned short u16;
typedef unsigned int u32;
typedef __attribute__((ext_vector_type(8))) short short8;
typedef __attribute__((ext_vector_type(4))) float f32x4;

// Round-to-nearest-even f32 -> bf16 bit pattern.
__device__ __forceinline__ u16 f2bf(float f) {
    union { float f; u32 u; } c; c.f = f;
    u32 x = c.u;
    return (u16)((x + 0x7fffu + ((x >> 16) & 1u)) >> 16);
}

// Async global->LDS, 16 bytes per lane. LDS dest must be wave-uniform base
// (HW writes base + lane*16); global src is per-lane.
__device__ __forceinline__ void gload16(const void* g, void* l) {
    __builtin_amdgcn_global_load_lds((const __attribute__((address_space(1))) void*)g,
                                     (__attribute__((address_space(3))) void*)l,
                                     16, 0, 0);
}

// All f32->bf16 conversions in one launch: blocks 0..4095 convert x,
// blocks 4096..8191 convert the four 1024x1024 weights (Wq,Wk,Wv->wqkv; Wo->wob).
__global__ void cvt_all_kernel(const float* __restrict__ x,
                               const float* __restrict__ wq, const float* __restrict__ wk,
                               const float* __restrict__ wv, const float* __restrict__ wo,
                               u16* __restrict__ xb, u16* __restrict__ wqkv,
                               u16* __restrict__ wob) {
    int bid = blockIdx.x;
    const float* src;
    u16* dst;
    int i;
    if (bid < 4096) {
        src = x; dst = xb;
        i = bid * 256 + threadIdx.x;
    } else {
        int w = (bid - 4096) >> 10;
        src = (w == 0) ? wq : (w == 1) ? wk : (w == 2) ? wv : wo;
        dst = (w < 3) ? (wqkv + (size_t)w * 1048576) : wob;
        i = ((bid - 4096) & 1023) * 256 + threadIdx.x;
    }
    float4 v = reinterpret_cast<const float4*>(src)[i];
    ushort4 o;
    o.x = f2bf(v.x); o.y = f2bf(v.y); o.z = f2bf(v.z); o.w = f2bf(v.w);
    reinterpret_cast<ushort4*>(dst)[i] = o;
}

// C(4096 x Ncols) = A(4096x1024) * B^T, B row-major (Ncols x 1024).
// m97 structure: global_load_lds dwordx4 staging, linear LDS + XOR-swizzled reads.
// MODE 0: f32 row-major to outf (Ncols=1024)
// MODE 1: fused QKV (Ncols=3072): gj>>10 selects Q / K / V-transposed layout.
//         Q is pre-scaled by 0.125*log2(e) so attention scores land in log2 units.
template<int MODE>
__global__ __launch_bounds__(256, 3) void gemm_nt(const u16* __restrict__ A,
                                                  const u16* __restrict__ Bw,
                                                  u16* __restrict__ qkv,
                                                  float* __restrict__ outf) {
    constexpr int K = 1024;
    __shared__ __align__(16) u16 Al[128 * 64];
    __shared__ __align__(16) u16 Bl[128 * 64];
    const int tid = threadIdx.x;
    const int row0 = blockIdx.y * 128, col0 = blockIdx.x * 128;
    const int wid = tid >> 6, lane = tid & 63;
    const int wr = wid >> 1, wc = wid & 1;       // 2x2 waves, each 64x64 output
    const int lr = lane & 15, lg = lane >> 4;
    f32x4 acc[4][4] = {};

    const int srow = tid >> 3;                   // staging row within 32-row group
    const int sslotbase = tid & 7;

    for (int kt = 0; kt < K; kt += 64) {
        __syncthreads();                         // prev compute done before overwrite
        #pragma unroll
        for (int i = 0; i < 4; ++i) {
            int row = srow + i * 32;
            int srcslot = sslotbase ^ (row & 7); // pre-swizzled source -> linear LDS dest
            int ldsoff = i * 2048 + wid * 512;   // u16 units; wave-uniform
            gload16(&A[(size_t)(row0 + row) * K + kt + srcslot * 8], &Al[ldsoff]);
            gload16(&Bw[(size_t)(col0 + row) * K + kt + srcslot * 8], &Bl[ldsoff]);
        }
        __syncthreads();                         // vmcnt(0) drained by compiler

        #pragma unroll
        for (int ks = 0; ks < 2; ++ks) {
            short8 af[4], bfr[4];
            #pragma unroll
            for (int m = 0; m < 4; ++m) {
                int row = wr * 64 + m * 16 + lr;
                af[m] = *reinterpret_cast<const short8*>(
                    &Al[row * 64 + (((ks * 4 + lg) ^ (lr & 7)) << 3)]);
            }
            #pragma unroll
            for (int n = 0; n < 4; ++n) {
                int row = wc * 64 + n * 16 + lr;
                bfr[n] = *reinterpret_cast<const short8*>(
                    &Bl[row * 64 + (((ks * 4 + lg) ^ (lr & 7)) << 3)]);
            }
            #pragma unroll
            for (int m = 0; m < 4; ++m)
                #pragma unroll
                for (int n = 0; n < 4; ++n)
                    acc[m][n] = __builtin_amdgcn_mfma_f32_16x16x32_bf16(af[m], bfr[n], acc[m][n], 0, 0, 0);
        }
    }

    #pragma unroll
    for (int m = 0; m < 4; ++m) {
        #pragma unroll
        for (int n = 0; n < 4; ++n) {
            #pragma unroll
            for (int r = 0; r < 4; ++r) {
                int gi = row0 + wr * 64 + m * 16 + lg * 4 + r;   // row = (lane>>4)*4+reg
                int gj = col0 + wc * 64 + n * 16 + lr;           // col = lane&15
                float v = acc[m][n][r];
                if (MODE == 0) {
                    outf[(size_t)gi * 1024 + gj] = v;
                } else {
                    int mat = gj >> 10, c = gj & 1023;
                    int h = c >> 6, hd = c & 63;
                    int b = gi >> 11, s = gi & 2047;
                    if (mat == 0) v *= 0.18033688f;   // Q *= 0.125*log2(e)
                    size_t idx;
                    if (mat < 2) idx = (((size_t)(b * 16 + h) * 2048) + s) * 64 + hd;   // Q,K: (B,H,S,HD)
                    else         idx = (((size_t)(b * 16 + h) * 64) + hd) * 2048 + s;   // V: (B,H,HD,S)
                    qkv[(size_t)mat * 4194304 + idx] = f2bf(v);
                }
            }
        }
    }
}

// Flash attention + ALiBi + causal, balanced pairing, diagonal-first, defer-max,
// FIXED-LOCAL bias in MFMA C + drifting running-max (global ALiBi offset absorbed
// as m_run += 64*slope2 per tile; cancels exactly in P, l, O), l-via-ones-MFMA.
// Sync: raw s_barrier + counted s_waitcnt vmcnt(8) -- prefetched global_load_lds
// stay in flight across the compute phase; no vmcnt(0)/lgkmcnt(0) drains in loop.
// Each 128-thread block (2 waves) owns q-strip pair {p, mirror(p)}: 33 units for all p.
// Grid: 1024 blocks, XCD-swizzled (each XCD sees 4 bh -> K/V L2-resident).
__global__ __launch_bounds__(128, 2) void attn_kernel(const u16* __restrict__ Q,
                                                      const u16* __restrict__ Kt,
                                                      const u16* __restrict__ VT,
                                                      u16* __restrict__ attn) {
    constexpr int S = 2048;
    __shared__ __align__(16) u16 Kl[2][64 * 64];
    __shared__ __align__(16) u16 Vl[2][64 * 64];
    __shared__ __align__(16) u16 Pl[4][16 * 64];   // [wid*2+strip]
    const int gid = blockIdx.x;
    const int base = gid >> 3, xcd = gid & 7;
    const int bh = xcd * 4 + (base >> 5);          // XCD x gets bh in [4x, 4x+4)
    const int p  = base & 31;                      // pair index 0..31
    const int b = bh >> 4, h = bh & 15;
    const int tid = threadIdx.x, wid = tid >> 6, lane = tid & 63;
    const int lr = lane & 15, lg = lane >> 4;
    const float slope2 = exp2f(-0.5f * (float)(h + 1)) * 1.44269504f;  // slope*log2(e)
    const int nt  = (2111 - 32 * p) >> 6;          // hi strip needs tiles 0..nt-1
    const int nlo = ((32 * p + 31) >> 6) + 1;      // lo strip active for t < nlo
    const int rowlo = 32 * p + wid * 16;
    const int rowhi = S - 32 * p - 32 + wid * 16;
    const size_t qkbase = (size_t)bh * S * 64;
    const size_t vbase  = (size_t)bh * 64 * S;

    // Q fragments (already scaled by 0.125*log2e in the GEMM epilogue)
    short8 qf[2][2];
    #pragma unroll
    for (int st = 0; st < 2; ++st) {
        int rb = st ? rowhi : rowlo;
        #pragma unroll
        for (int ks = 0; ks < 2; ++ks)
            qf[st][ks] = *reinterpret_cast<const short8*>(
                &Q[qkbase + (size_t)(rb + lr) * 64 + ks * 32 + lg * 8]);
    }

    // Fixed LOCAL ALiBi bias (tile- and strip-independent, log2 units) as MFMA C-init.
    // The global offset slope2*(rowbase - kv0) drifts into m_run (+= 64*slope2/tile);
    // it cancels in P = exp2(S_shift - m_shift), so l and O are unaffected.
    f32x4 bias[4];
    #pragma unroll
    for (int n = 0; n < 4; ++n)
        #pragma unroll
        for (int r = 0; r < 4; ++r)
            bias[n][r] = slope2 * (float)((n * 16 + lr) - (lg * 4 + r));

    const float mstep = slope2 * 64.f;             // shift growth per descending tile
    float m_run[2][4];
    f32x4 o_acc[2][4] = {};
    f32x4 l_acc[2] = {};
    #pragma unroll
    for (int st = 0; st < 2; ++st)
        #pragma unroll
        for (int r = 0; r < 4; ++r) m_run[st][r] = -1e30f;

    short8 bones = (short8)(short)0x3F80;          // bf16 1.0 splat (l = P @ ones)

    const int srow = tid >> 3;    // 0..15
    const int sslot = tid & 7;

    // 8 gload16 per wave per tile (K: 4, V: 4).
    #define STAGE(buf, kv)                                                          \
        do {                                                                        \
            _Pragma("unroll")                                                       \
            for (int i_ = 0; i_ < 4; ++i_) {                                        \
                int row_ = srow + i_ * 16;                                          \
                int ss_ = sslot ^ (row_ & 7);                                       \
                int lo_ = i_ * 1024 + wid * 512;                                    \
                gload16(&Kt[qkbase + (size_t)((kv) * 64 + row_) * 64 + ss_ * 8],    \
                        &Kl[buf][lo_]);                                             \
                gload16(&VT[vbase + (size_t)row_ * S + (kv) * 64 + ss_ * 8],        \
                        &Vl[buf][lo_]);                                             \
            }                                                                       \
        } while (0)

    // softmax for one strip: defer-max common path has NO cross-lane ops.
    auto softmax = [&](f32x4* sacc, int st, bool domask, int rowbase, int kv0) {
        float* mr = m_run[st];
        if (domask) {
            #pragma unroll
            for (int n = 0; n < 4; ++n)
                #pragma unroll
                for (int r = 0; r < 4; ++r) {
                    int gc = kv0 + n * 16 + lr, gr = rowbase + lg * 4 + r;
                    if (gc > gr) sacc[n][r] = -1e30f;
                }
        }
        float mxl[4];
        #pragma unroll
        for (int r = 0; r < 4; ++r)
            mxl[r] = fmaxf(fmaxf(sacc[0][r], sacc[1][r]), fmaxf(sacc[2][r], sacc[3][r]));
        int ok = (mxl[0] <= mr[0] + 8.f) && (mxl[1] <= mr[1] + 8.f) &&
                 (mxl[2] <= mr[2] + 8.f) && (mxl[3] <= mr[3] + 8.f);
        if (!__all(ok)) {
            #pragma unroll
            for (int r = 0; r < 4; ++r) {
                float mx = mxl[r];
                mx = fmaxf(mx, __shfl_xor(mx, 1));
                mx = fmaxf(mx, __shfl_xor(mx, 2));
                mx = fmaxf(mx, __shfl_xor(mx, 4));
                mx = fmaxf(mx, __shfl_xor(mx, 8));
                float mnew = fmaxf(mr[r], mx);
                float resc = exp2f(mr[r] - mnew);
                mr[r] = mnew;
                l_acc[st][r] *= resc;
                #pragma unroll
                for (int nd = 0; nd < 4; ++nd) o_acc[st][nd][r] *= resc;
            }
        }
        u16* pb = &Pl[wid * 2 + st][0];
        #pragma unroll
        for (int r = 0; r < 4; ++r) {
            int pr = lg * 4 + r;
            #pragma unroll
            for (int n = 0; n < 4; ++n) {
                float pe = exp2f(sacc[n][r] - mr[r]);
                // round-half-up cvt: bias cancels exactly in O/l (same P feeds both)
                u32 bits = __float_as_uint(pe);
                int pc = n * 16 + lr;
                pb[pr * 64 + (((pc >> 3) ^ (pr & 7)) << 3) + (pc & 7)] =
                    (u16)((bits + 0x8000u) >> 16);
            }
        }
    };

    const int tstart = nt - 1;
    STAGE(tstart & 1, tstart);

    for (int t = tstart; t >= 0; --t) {          // diagonal-first
        const int cur = t & 1;
        const int kv0 = t * 64;
        if (t > 0) {
            STAGE(cur ^ 1, t - 1);               // prefetch next (lower) tile
            asm volatile("s_waitcnt vmcnt(8)" ::: "memory");   // my tile-t loads landed
        } else {
            asm volatile("s_waitcnt vmcnt(0)" ::: "memory");
        }
        __builtin_amdgcn_s_barrier();            // all waves' tile-t loads landed
        const bool lo_on = (t < nlo);            // block-uniform

        // shift domain moves with the tile: m_shift(t) = m_shift(t+1) + 64*slope2
        #pragma unroll
        for (int st = 0; st < 2; ++st)
            #pragma unroll
            for (int r = 0; r < 4; ++r) m_run[st][r] += mstep;

        // ---- S = Q K^T (C-init = fixed local bias) ----
        f32x4 shi[4], slo[4];
        __builtin_amdgcn_s_setprio(1);
        #pragma unroll
        for (int ks = 0; ks < 2; ++ks) {
            const int sz = ((ks * 4 + lg) ^ (lr & 7)) << 3;
            short8 bk[4];
            #pragma unroll
            for (int n = 0; n < 4; ++n)
                bk[n] = *reinterpret_cast<const short8*>(&Kl[cur][(n * 16 + lr) * 64 + sz]);
            #pragma unroll
            for (int n = 0; n < 4; ++n)
                shi[n] = __builtin_amdgcn_mfma_f32_16x16x32_bf16(qf[1][ks], bk[n],
                                                                 ks ? shi[n] : bias[n], 0, 0, 0);
            if (lo_on)
                #pragma unroll
                for (int n = 0; n < 4; ++n)
                    slo[n] = __builtin_amdgcn_mfma_f32_16x16x32_bf16(qf[0][ks], bk[n],
                                                                     ks ? slo[n] : bias[n], 0, 0, 0);
        }
        __builtin_amdgcn_s_setprio(0);

        softmax(shi, 1, t == nt - 1, rowhi, kv0);
        if (lo_on)
            softmax(slo, 0, t == nlo - 1, rowlo, kv0);

        // ---- O += P V; l += P @ 1 ----
        __builtin_amdgcn_s_setprio(1);
        #pragma unroll
        for (int ks = 0; ks < 2; ++ks) {
            const int sz = ((ks * 4 + lg) ^ (lr & 7)) << 3;
            short8 bv[4];
            #pragma unroll
            for (int nd = 0; nd < 4; ++nd)
                bv[nd] = *reinterpret_cast<const short8*>(&Vl[cur][(nd * 16 + lr) * 64 + sz]);
            short8 ah = *reinterpret_cast<const short8*>(&Pl[wid * 2 + 1][lr * 64 + sz]);
            #pragma unroll
            for (int nd = 0; nd < 4; ++nd)
                o_acc[1][nd] = __builtin_amdgcn_mfma_f32_16x16x32_bf16(ah, bv[nd], o_acc[1][nd], 0, 0, 0);
            l_acc[1] = __builtin_amdgcn_mfma_f32_16x16x32_bf16(ah, bones, l_acc[1], 0, 0, 0);
            if (lo_on) {
                short8 al = *reinterpret_cast<const short8*>(&Pl[wid * 2 + 0][lr * 64 + sz]);
                #pragma unroll
                for (int nd = 0; nd < 4; ++nd)
                    o_acc[0][nd] = __builtin_amdgcn_mfma_f32_16x16x32_bf16(al, bv[nd], o_acc[0][nd], 0, 0, 0);
                l_acc[0] = __builtin_amdgcn_mfma_f32_16x16x32_bf16(al, bones, l_acc[0], 0, 0, 0);
            }
        }
        __builtin_amdgcn_s_setprio(0);
        __builtin_amdgcn_s_barrier();            // all waves done with buf[cur];
                                                 // next iter's STAGE may overwrite it
    }
    #undef STAGE

    // epilogue: O / l -> (B,S,D) bf16, D index = h*64 + hd  (no m fixup needed:
    // the shift cancels inside P, so l and O are already in the true domain)
    #pragma unroll
    for (int st = 0; st < 2; ++st) {
        int rb = st ? rowhi : rowlo;
        #pragma unroll
        for (int r = 0; r < 4; ++r) {
            float inv = 1.f / l_acc[st][r];
            int gs = rb + lg * 4 + r;
            size_t obase = ((size_t)b * S + gs) * 1024 + h * 64;
            #pragma unroll
            for (int nd = 0; nd < 4; ++nd)
                attn[obase + nd * 16 + lr] = f2bf(o_acc[st][nd][r] * inv);
        }
    }
}

extern "C" void kernel_launch(void* const* d_in, const int* in_sizes, int n_in,
                              void* d_out, int out_size, void* d_ws, size_t ws_size,
                              hipStream_t stream) {
    const float* x  = (const float*)d_in[0];
    // d_in[1] is the causal mask (fixed tril) — implemented analytically.
    const float* Wq = (const float*)d_in[2];
    const float* Wk = (const float*)d_in[3];
    const float* Wv = (const float*)d_in[4];
    const float* Wo = (const float*)d_in[5];

    u16* xb   = (u16*)d_ws;            // 4,194,304  (also reused as Ab)
    u16* wqkv = xb + 4194304;          // 3,145,728  (Wq;Wk;Wv rows)
    u16* wob  = wqkv + 3145728;        // 1,048,576
    u16* Qb   = wob + 1048576;         // 4,194,304  (B,H,S,HD)
    u16* Kb   = Qb + 4194304;          // 4,194,304  (B,H,S,HD)
    u16* VTb  = Kb + 4194304;          // 4,194,304  (B,H,HD,S)
    u16* Ab   = xb;                    // attn output reuses xb (x no longer needed)

    cvt_all_kernel<<<8192, 256, 0, stream>>>(x, Wq, Wk, Wv, Wo, xb, wqkv, wob);

    gemm_nt<1><<<dim3(24, 32), 256, 0, stream>>>(xb, wqkv, Qb, nullptr);   // fused QKV

    attn_kernel<<<1024, 128, 0, stream>>>(Qb, Kb, VTb, Ab);

    gemm_nt<0><<<dim3(8, 32), 256, 0, stream>>>(Ab, wob, nullptr, (float*)d_out);
}

// Round 9
// 118.926 us; speedup vs baseline: 4.1325x; 1.0231x over previous
//
#include <hip/hip_runtime.h>
#include <hip/hip_bf16.h>

typedef unsigned short u16;
typedef unsigned int u32;
typedef __attribute__((ext_vector_type(8))) short short8;
typedef __attribute__((ext_vector_type(4))) float f32x4;

// Round-to-nearest-even f32 -> bf16 bit pattern.
__device__ __forceinline__ u16 f2bf(float f) {
    union { float f; u32 u; } c; c.f = f;
    u32 x = c.u;
    return (u16)((x + 0x7fffu + ((x >> 16) & 1u)) >> 16);
}

// Async global->LDS, 16 bytes per lane. LDS dest must be wave-uniform base
// (HW writes base + lane*16); global src is per-lane.
__device__ __forceinline__ void gload16(const void* g, void* l) {
    __builtin_amdgcn_global_load_lds((const __attribute__((address_space(1))) void*)g,
                                     (__attribute__((address_space(3))) void*)l,
                                     16, 0, 0);
}

// All f32->bf16 conversions in one launch: blocks 0..4095 convert x,
// blocks 4096..8191 convert the four 1024x1024 weights (Wq,Wk,Wv->wqkv; Wo->wob).
__global__ void cvt_all_kernel(const float* __restrict__ x,
                               const float* __restrict__ wq, const float* __restrict__ wk,
                               const float* __restrict__ wv, const float* __restrict__ wo,
                               u16* __restrict__ xb, u16* __restrict__ wqkv,
                               u16* __restrict__ wob) {
    int bid = blockIdx.x;
    const float* src;
    u16* dst;
    int i;
    if (bid < 4096) {
        src = x; dst = xb;
        i = bid * 256 + threadIdx.x;
    } else {
        int w = (bid - 4096) >> 10;
        src = (w == 0) ? wq : (w == 1) ? wk : (w == 2) ? wv : wo;
        dst = (w < 3) ? (wqkv + (size_t)w * 1048576) : wob;
        i = ((bid - 4096) & 1023) * 256 + threadIdx.x;
    }
    float4 v = reinterpret_cast<const float4*>(src)[i];
    ushort4 o;
    o.x = f2bf(v.x); o.y = f2bf(v.y); o.z = f2bf(v.z); o.w = f2bf(v.w);
    reinterpret_cast<ushort4*>(dst)[i] = o;
}

// C(4096 x Ncols) = A(4096x1024) * B^T, B row-major (Ncols x 1024).
// m97 structure: global_load_lds dwordx4 staging, linear LDS + XOR-swizzled reads.
// MODE 0: f32 row-major to outf (Ncols=1024)
// MODE 1: fused QKV (Ncols=3072): gj>>10 selects Q / K / V-transposed layout.
//         Q is pre-scaled by 0.125*log2(e) so attention scores land in log2 units.
template<int MODE>
__global__ __launch_bounds__(256, 3) void gemm_nt(const u16* __restrict__ A,
                                                  const u16* __restrict__ Bw,
                                                  u16* __restrict__ qkv,
                                                  float* __restrict__ outf) {
    constexpr int K = 1024;
    __shared__ __align__(16) u16 Al[128 * 64];
    __shared__ __align__(16) u16 Bl[128 * 64];
    const int tid = threadIdx.x;
    const int row0 = blockIdx.y * 128, col0 = blockIdx.x * 128;
    const int wid = tid >> 6, lane = tid & 63;
    const int wr = wid >> 1, wc = wid & 1;       // 2x2 waves, each 64x64 output
    const int lr = lane & 15, lg = lane >> 4;
    f32x4 acc[4][4] = {};

    const int srow = tid >> 3;                   // staging row within 32-row group
    const int sslotbase = tid & 7;

    for (int kt = 0; kt < K; kt += 64) {
        __syncthreads();                         // prev compute done before overwrite
        #pragma unroll
        for (int i = 0; i < 4; ++i) {
            int row = srow + i * 32;
            int srcslot = sslotbase ^ (row & 7); // pre-swizzled source -> linear LDS dest
            int ldsoff = i * 2048 + wid * 512;   // u16 units; wave-uniform
            gload16(&A[(size_t)(row0 + row) * K + kt + srcslot * 8], &Al[ldsoff]);
            gload16(&Bw[(size_t)(col0 + row) * K + kt + srcslot * 8], &Bl[ldsoff]);
        }
        __syncthreads();                         // vmcnt(0) drained by compiler

        #pragma unroll
        for (int ks = 0; ks < 2; ++ks) {
            short8 af[4], bfr[4];
            #pragma unroll
            for (int m = 0; m < 4; ++m) {
                int row = wr * 64 + m * 16 + lr;
                af[m] = *reinterpret_cast<const short8*>(
                    &Al[row * 64 + (((ks * 4 + lg) ^ (lr & 7)) << 3)]);
            }
            #pragma unroll
            for (int n = 0; n < 4; ++n) {
                int row = wc * 64 + n * 16 + lr;
                bfr[n] = *reinterpret_cast<const short8*>(
                    &Bl[row * 64 + (((ks * 4 + lg) ^ (lr & 7)) << 3)]);
            }
            #pragma unroll
            for (int m = 0; m < 4; ++m)
                #pragma unroll
                for (int n = 0; n < 4; ++n)
                    acc[m][n] = __builtin_amdgcn_mfma_f32_16x16x32_bf16(af[m], bfr[n], acc[m][n], 0, 0, 0);
        }
    }

    #pragma unroll
    for (int m = 0; m < 4; ++m) {
        #pragma unroll
        for (int n = 0; n < 4; ++n) {
            #pragma unroll
            for (int r = 0; r < 4; ++r) {
                int gi = row0 + wr * 64 + m * 16 + lg * 4 + r;   // row = (lane>>4)*4+reg
                int gj = col0 + wc * 64 + n * 16 + lr;           // col = lane&15
                float v = acc[m][n][r];
                if (MODE == 0) {
                    outf[(size_t)gi * 1024 + gj] = v;
                } else {
                    int mat = gj >> 10, c = gj & 1023;
                    int h = c >> 6, hd = c & 63;
                    int b = gi >> 11, s = gi & 2047;
                    if (mat == 0) v *= 0.18033688f;   // Q *= 0.125*log2(e)
                    size_t idx;
                    if (mat < 2) idx = (((size_t)(b * 16 + h) * 2048) + s) * 64 + hd;   // Q,K: (B,H,S,HD)
                    else         idx = (((size_t)(b * 16 + h) * 64) + hd) * 2048 + s;   // V: (B,H,HD,S)
                    qkv[(size_t)mat * 4194304 + idx] = f2bf(v);
                }
            }
        }
    }
}

// Flash attention + ALiBi + causal.
// ONE 16-row q-strip PER WAVE, 2 waves/block (rows 32*qb .. 32*qb+31), KVBLK=64,
// SINGLE-buffered K/V in LDS -> 20 KB/block -> 8 blocks/CU = 16 waves/CU (4/SIMD).
// Grid: 2048 blocks, qb DESCENDING (LPT balance), XCD-swizzled (4 bh per XCD).
// Diagonal-first + defer-max + fixed-local bias in MFMA C + drifting running-max
// + l-via-ones-MFMA. 2 __syncthreads per tile; load latency covered by 2x TLP.
__global__ __launch_bounds__(128, 4) void attn_kernel(const u16* __restrict__ Q,
                                                      const u16* __restrict__ Kt,
                                                      const u16* __restrict__ VT,
                                                      u16* __restrict__ attn) {
    constexpr int S = 2048;
    __shared__ __align__(16) u16 Kl[64 * 64];      // [kv][hd]
    __shared__ __align__(16) u16 Vl[64 * 64];      // [hd][kv] (VT tile)
    __shared__ __align__(16) u16 Pl[2][16 * 64];   // per-wave P
    const int gid = blockIdx.x;
    const int base = gid >> 3, xcd = gid & 7;
    const int bh = xcd * 4 + (base & 3);           // XCD x gets bh in [4x, 4x+4)
    const int qb = 63 - (base >> 2);               // descending work size (LPT)
    const int b = bh >> 4, h = bh & 15;
    const int tid = threadIdx.x, wid = tid >> 6, lane = tid & 63;
    const int lr = lane & 15, lg = lane >> 4;
    const float slope2 = exp2f(-0.5f * (float)(h + 1)) * 1.44269504f;  // slope*log2(e)
    const int nt = (qb + 2) >> 1;                  // tiles 0..nt-1; mask only at nt-1
    const int rowq = 32 * qb + wid * 16;           // this wave's first q row
    const size_t qkbase = (size_t)bh * S * 64;
    const size_t vbase  = (size_t)bh * 64 * S;

    // Q fragments (already scaled by 0.125*log2e in the GEMM epilogue)
    short8 qf[2];
    #pragma unroll
    for (int ks = 0; ks < 2; ++ks)
        qf[ks] = *reinterpret_cast<const short8*>(
            &Q[qkbase + (size_t)(rowq + lr) * 64 + ks * 32 + lg * 8]);

    // Fixed LOCAL ALiBi bias (tile-independent, log2 units) as MFMA C-init.
    // Global offset slope2*(rowq - kv0) drifts into m_run (+= 64*slope2/tile);
    // it cancels in P = exp2(S_shift - m_shift), so l and O are unaffected.
    f32x4 bias[4];
    #pragma unroll
    for (int n = 0; n < 4; ++n)
        #pragma unroll
        for (int r = 0; r < 4; ++r)
            bias[n][r] = slope2 * (float)((n * 16 + lr) - (lg * 4 + r));

    const float mstep = slope2 * 64.f;             // shift growth per descending tile
    float m_run[4] = {-1e30f, -1e30f, -1e30f, -1e30f};
    f32x4 o_acc[4] = {};
    f32x4 l_acc = {};

    short8 bones = (short8)(short)0x3F80;          // bf16 1.0 splat (l = P @ ones)

    const int srow = tid >> 3;    // 0..15
    const int sslot = tid & 7;

    // 8 gload16 per wave per tile (K: 4, V: 4). Linear LDS dest, pre-swizzled src.
    #define STAGE(kv)                                                               \
        do {                                                                        \
            _Pragma("unroll")                                                       \
            for (int i_ = 0; i_ < 4; ++i_) {                                        \
                int row_ = srow + i_ * 16;                                          \
                int ss_ = sslot ^ (row_ & 7);                                       \
                int lo_ = i_ * 1024 + wid * 512;                                    \
                gload16(&Kt[qkbase + (size_t)((kv) * 64 + row_) * 64 + ss_ * 8],    \
                        &Kl[lo_]);                                                  \
                gload16(&VT[vbase + (size_t)row_ * S + (kv) * 64 + ss_ * 8],        \
                        &Vl[lo_]);                                                  \
            }                                                                       \
        } while (0)

    STAGE(nt - 1);

    for (int t = nt - 1; t >= 0; --t) {            // diagonal-first
        const int kv0 = t * 64;
        __syncthreads();                           // vmcnt(0)+lgkmcnt(0)+barrier:
                                                   // all waves' staged tile visible
        // shift domain moves with the tile
        #pragma unroll
        for (int r = 0; r < 4; ++r) m_run[r] += mstep;

        // ---- S = Q K^T (C-init = fixed local bias) ----
        f32x4 sacc[4];
        __builtin_amdgcn_s_setprio(1);
        #pragma unroll
        for (int ks = 0; ks < 2; ++ks) {
            const int sz = ((ks * 4 + lg) ^ (lr & 7)) << 3;
            #pragma unroll
            for (int n = 0; n < 4; ++n) {
                short8 bk = *reinterpret_cast<const short8*>(&Kl[(n * 16 + lr) * 64 + sz]);
                sacc[n] = __builtin_amdgcn_mfma_f32_16x16x32_bf16(qf[ks], bk,
                                                                  ks ? sacc[n] : bias[n], 0, 0, 0);
            }
        }
        __builtin_amdgcn_s_setprio(0);

        // ---- online softmax: defer-max common path has NO cross-lane ops ----
        if (t == nt - 1) {                         // only the diagonal tile masks
            #pragma unroll
            for (int n = 0; n < 4; ++n)
                #pragma unroll
                for (int r = 0; r < 4; ++r) {
                    int gc = kv0 + n * 16 + lr, gr = rowq + lg * 4 + r;
                    if (gc > gr) sacc[n][r] = -1e30f;
                }
        }
        {
            float mxl[4];
            #pragma unroll
            for (int r = 0; r < 4; ++r)
                mxl[r] = fmaxf(fmaxf(sacc[0][r], sacc[1][r]), fmaxf(sacc[2][r], sacc[3][r]));
            int ok = (mxl[0] <= m_run[0] + 8.f) && (mxl[1] <= m_run[1] + 8.f) &&
                     (mxl[2] <= m_run[2] + 8.f) && (mxl[3] <= m_run[3] + 8.f);
            if (!__all(ok)) {
                #pragma unroll
                for (int r = 0; r < 4; ++r) {
                    float mx = mxl[r];
                    mx = fmaxf(mx, __shfl_xor(mx, 1));
                    mx = fmaxf(mx, __shfl_xor(mx, 2));
                    mx = fmaxf(mx, __shfl_xor(mx, 4));
                    mx = fmaxf(mx, __shfl_xor(mx, 8));
                    float mnew = fmaxf(m_run[r], mx);
                    float resc = exp2f(m_run[r] - mnew);
                    m_run[r] = mnew;
                    l_acc[r] *= resc;
                    #pragma unroll
                    for (int nd = 0; nd < 4; ++nd) o_acc[nd][r] *= resc;
                }
            }
            u16* pb = &Pl[wid][0];
            #pragma unroll
            for (int r = 0; r < 4; ++r) {
                int pr = lg * 4 + r;
                #pragma unroll
                for (int n = 0; n < 4; ++n) {
                    float pe = exp2f(sacc[n][r] - m_run[r]);
                    // truncating cvt: deterministic per-element, cancels in O/l
                    u32 bits = __float_as_uint(pe);
                    int pc = n * 16 + lr;
                    pb[pr * 64 + (((pc >> 3) ^ (pr & 7)) << 3) + (pc & 7)] =
                        (u16)(bits >> 16);
                }
            }
        }

        // ---- O += P V; l += P @ 1 ----
        __builtin_amdgcn_s_setprio(1);
        #pragma unroll
        for (int ks = 0; ks < 2; ++ks) {
            const int sz = ((ks * 4 + lg) ^ (lr & 7)) << 3;
            short8 ap = *reinterpret_cast<const short8*>(&Pl[wid][lr * 64 + sz]);
            #pragma unroll
            for (int nd = 0; nd < 4; ++nd) {
                short8 bv = *reinterpret_cast<const short8*>(&Vl[(nd * 16 + lr) * 64 + sz]);
                o_acc[nd] = __builtin_amdgcn_mfma_f32_16x16x32_bf16(ap, bv, o_acc[nd], 0, 0, 0);
            }
            l_acc = __builtin_amdgcn_mfma_f32_16x16x32_bf16(ap, bones, l_acc, 0, 0, 0);
        }
        __builtin_amdgcn_s_setprio(0);

        if (t > 0) {
            __syncthreads();                       // all waves done with K/V tile
            STAGE(t - 1);                          // overwrite with next (lower) tile
        }
    }
    #undef STAGE

    // epilogue: O / l -> (B,S,D) bf16, D index = h*64 + hd  (shift cancels in P,
    // so l and O are already in the true domain)
    #pragma unroll
    for (int r = 0; r < 4; ++r) {
        float inv = 1.f / l_acc[r];
        int gs = rowq + lg * 4 + r;
        size_t obase = ((size_t)b * S + gs) * 1024 + h * 64;
        #pragma unroll
        for (int nd = 0; nd < 4; ++nd)
            attn[obase + nd * 16 + lr] = f2bf(o_acc[nd][r] * inv);
    }
}

extern "C" void kernel_launch(void* const* d_in, const int* in_sizes, int n_in,
                              void* d_out, int out_size, void* d_ws, size_t ws_size,
                              hipStream_t stream) {
    const float* x  = (const float*)d_in[0];
    // d_in[1] is the causal mask (fixed tril) — implemented analytically.
    const float* Wq = (const float*)d_in[2];
    const float* Wk = (const float*)d_in[3];
    const float* Wv = (const float*)d_in[4];
    const float* Wo = (const float*)d_in[5];

    u16* xb   = (u16*)d_ws;            // 4,194,304  (also reused as Ab)
    u16* wqkv = xb + 4194304;          // 3,145,728  (Wq;Wk;Wv rows)
    u16* wob  = wqkv + 3145728;        // 1,048,576
    u16* Qb   = wob + 1048576;         // 4,194,304  (B,H,S,HD)
    u16* Kb   = Qb + 4194304;          // 4,194,304  (B,H,S,HD)
    u16* VTb  = Kb + 4194304;          // 4,194,304  (B,H,HD,S)
    u16* Ab   = xb;                    // attn output reuses xb (x no longer needed)

    cvt_all_kernel<<<8192, 256, 0, stream>>>(x, Wq, Wk, Wv, Wo, xb, wqkv, wob);

    gemm_nt<1><<<dim3(24, 32), 256, 0, stream>>>(xb, wqkv, Qb, nullptr);   // fused QKV

    attn_kernel<<<2048, 128, 0, stream>>>(Qb, Kb, VTb, Ab);

    gemm_nt<0><<<dim3(8, 32), 256, 0, stream>>>(Ab, wob, nullptr, (float*)d_out);
}